// Round 3
// baseline (183.995 us; speedup 1.0000x reference)
//
#include <hip/hip_runtime.h>
#include <cstdint>

typedef short bf16x8 __attribute__((ext_vector_type(8)));
typedef float f32x4 __attribute__((ext_vector_type(4)));

__device__ __forceinline__ unsigned short f2bf(float f) {
  unsigned u = __builtin_bit_cast(unsigned, f);
  u += 0x7fffu + ((u >> 16) & 1u);  // RNE
  return (unsigned short)(u >> 16);
}
__device__ __forceinline__ float bflo(unsigned u) {
  return __builtin_bit_cast(float, u << 16);
}
__device__ __forceinline__ float bfhi(unsigned u) {
  return __builtin_bit_cast(float, u & 0xffff0000u);
}
__device__ __forceinline__ float fast_tanh(float x) {
  float e = __builtin_amdgcn_exp2f(x * 2.885390081777927f);
  return 1.0f - 2.0f * __builtin_amdgcn_rcpf(e + 1.0f);
}

#if __has_builtin(__builtin_amdgcn_fdot2_f32_bf16)
typedef __bf16 bf16x2 __attribute__((ext_vector_type(2)));
__device__ __forceinline__ float dot2bf(unsigned a, unsigned b, float c) {
  return __builtin_amdgcn_fdot2_f32_bf16(__builtin_bit_cast(bf16x2, a),
                                         __builtin_bit_cast(bf16x2, b), c,
                                         false);
}
#else
__device__ __forceinline__ float dot2bf(unsigned a, unsigned b, float c) {
  c = fmaf(bflo(a), bflo(b), c);
  c = fmaf(bfhi(a), bfhi(b), c);
  return c;
}
#endif

// ---------------------------------------------------------------------------
// Stage 1: per-(bt,co,ksplit) partial GEMM, M=64(ipos) N=64(kpos) K=1024/S.
// Register ping-pong prefetch hides global latency; epilogue transposes C
// through LDS so stores are coalesced b128 into part[ks][bt][co][pos 4096].
// NO bias/tanh here (deferred to stage23 staging; partials are linear).
// ---------------------------------------------------------------------------
template <int ITERS>
__global__ __launch_bounds__(256) void k_stage1(const float* __restrict__ x,
                                                const float* __restrict__ w1,
                                                float* __restrict__ part) {
  __shared__ __align__(16) char lds_raw[64 * 65 * 4];      // 16640 B
  unsigned short* As = (unsigned short*)lds_raw;           // 64 rows * 40 hw
  unsigned short* Bs = (unsigned short*)(lds_raw + 5120);  // 64 rows * 40 hw
  float* Cs = (float*)lds_raw;                             // 64 x 65 fp32

  const int tid = threadIdx.x;
  const int ks = blockIdx.x >> 7;
  const int bt = (blockIdx.x >> 3) & 15;
  const int co = blockIdx.x & 7;
  const int w = tid >> 6, lane = tid & 63, lm = lane & 15, q = lane >> 4;
  const int rrow = tid & 63, kgr = tid >> 6;

  f32x4 acc[4];
#pragma unroll
  for (int i = 0; i < 4; ++i) acc[i] = (f32x4){0.f, 0.f, 0.f, 0.f};

  const float* gA = x + (bt << 16) + ((size_t)(ks * ITERS * 32) << 6);
  const float* gB = w1 + (co << 6) + (size_t)(ks * ITERS * 32) * 512;

  float va[2][8], vb[2][8];
#define S1_LOAD(buf, it)                                     \
  {                                                          \
    const int kb = (it) * 32 + (kgr << 3);                   \
    _Pragma("unroll") for (int j = 0; j < 8; ++j) {          \
      va[buf][j] = gA[((kb + j) << 6) | rrow];               \
      vb[buf][j] = gB[(kb + j) * 512 + rrow];                \
    }                                                        \
  }
  S1_LOAD(0, 0);
#pragma unroll
  for (int it = 0; it < ITERS; ++it) {
    const int cur = it & 1;
    if (it + 1 < ITERS) S1_LOAD(cur ^ 1, it + 1);
    uint4 pa, pb;
    pa.x = f2bf(va[cur][0]) | ((unsigned)f2bf(va[cur][1]) << 16);
    pa.y = f2bf(va[cur][2]) | ((unsigned)f2bf(va[cur][3]) << 16);
    pa.z = f2bf(va[cur][4]) | ((unsigned)f2bf(va[cur][5]) << 16);
    pa.w = f2bf(va[cur][6]) | ((unsigned)f2bf(va[cur][7]) << 16);
    pb.x = f2bf(vb[cur][0]) | ((unsigned)f2bf(vb[cur][1]) << 16);
    pb.y = f2bf(vb[cur][2]) | ((unsigned)f2bf(vb[cur][3]) << 16);
    pb.z = f2bf(vb[cur][4]) | ((unsigned)f2bf(vb[cur][5]) << 16);
    pb.w = f2bf(vb[cur][6]) | ((unsigned)f2bf(vb[cur][7]) << 16);
    *(uint4*)&As[rrow * 40 + (kgr << 3)] = pa;
    *(uint4*)&Bs[rrow * 40 + (kgr << 3)] = pb;
    __syncthreads();
    bf16x8 a = *(const bf16x8*)&As[((w << 4) + lm) * 40 + (q << 3)];
#pragma unroll
    for (int nf = 0; nf < 4; ++nf) {
      bf16x8 b = *(const bf16x8*)&Bs[((nf << 4) + lm) * 40 + (q << 3)];
      acc[nf] = __builtin_amdgcn_mfma_f32_16x16x32_bf16(a, b, acc[nf], 0, 0, 0);
    }
    __syncthreads();
  }
#undef S1_LOAD
  // ---- epilogue: C -> LDS -> coalesced b128 stores (pos-linear layout)
#pragma unroll
  for (int nf = 0; nf < 4; ++nf)
#pragma unroll
    for (int r = 0; r < 4; ++r) {
      int m = (w << 4) + (q << 2) + r;
      int n = (nf << 4) + lm;
      Cs[m * 65 + n] = acc[nf][r];
    }
  __syncthreads();
  float* dst = part + ((size_t)((((ks << 4) + bt) << 3) + co) << 12);
  float ov[16];
#pragma unroll
  for (int j = 0; j < 16; ++j) {
    int pos = (tid << 4) + j;
    int z = pos >> 8, y = (pos >> 4) & 15, xx = pos & 15;
    int m = ((z >> 2) << 4) + ((y >> 2) << 2) + (xx >> 2);
    int n = ((z & 3) << 4) + ((y & 3) << 2) + (xx & 3);
    ov[j] = Cs[m * 65 + n];
  }
#pragma unroll
  for (int j = 0; j < 4; ++j)
    *(f32x4*)(dst + (tid << 4) + (j << 2)) = *(const f32x4*)&ov[j << 2];
}

// ---------------------------------------------------------------------------
// Fused stage 2+3. h1s staging sums the K-split partials + b1 + tanh.
// w2s uses bank-tiling strides (784,196,40,8): the 8 (kz,ky) combos per wave
// land on disjoint 4-bank windows -> conflict-free broadcast loads.
// Fill parallelized over 1224 half-row units (wz, wy, xhalf).
// ---------------------------------------------------------------------------
__global__ __launch_bounds__(256) void k_stage23(
    const float* __restrict__ part, const float* __restrict__ w2,
    const float* __restrict__ b2, const float* __restrict__ w3,
    const float* __restrict__ b3, const float* __restrict__ b1,
    float* __restrict__ out, int nsplit) {
  __shared__ __align__(16) unsigned win_d[18 * 34 * 12];  // 29376 B
  __shared__ __align__(16) float h1s[6 * 520];            // [uz]520+[uy]52+[ux]8+ci
  __shared__ __align__(16) float w2s[6272];               // swizzled, 25088 B
  __shared__ __align__(16) unsigned w3p[1024];            // [cio][kd][kh][pair][c4]

  const int tid = threadIdx.x;
  const int bid = blockIdx.x;
  const int bt = bid >> 5;
  const int tile = bid & 31;
  const int tz = tile >> 3, ty = (tile >> 2) & 1, tx = tile & 3;
  const int Z0 = tz << 3, Y0 = ty << 4, X0 = tx << 3;
  const int Qz0 = (Z0 << 1) - 1, Qy0 = (Y0 << 1) - 1, Qx0 = (X0 << 1) - 1;
  const int Uz0 = (tz << 2) - 1, Uy0 = (ty << 3) - 1, Ux0 = (tx << 2) - 1;

  // ---- staging: h1 = tanh(sum_s part + b1), gather into padded LDS
  for (int l = tid; l < 2880; l += 256) {
    int ux = l % 6;
    int t1 = l / 6;
    int uy = t1 % 10;
    int t2 = t1 / 10;
    int uz = t2 % 6;
    int ci = t2 / 6;
    int gz = Uz0 + uz, gy = Uy0 + uy, gx = Ux0 + ux;
    float v = 0.f;
    if ((unsigned)gz < 16u && (unsigned)gy < 16u && (unsigned)gx < 16u) {
      const float* p =
          part + ((size_t)((bt << 3) + ci) << 12) + (gz << 8) + (gy << 4) + gx;
      float s = b1[ci];
      for (int sg = 0; sg < nsplit; ++sg) s += p[(size_t)sg << 19];
      v = fast_tanh(s);
    }
    h1s[uz * 520 + uy * 52 + (ux << 3) + ci] = v;
  }
  for (int l = tid; l < 4096; l += 256) {
    int ci = l & 7;
    int r = l >> 3;
    int kpos = r & 63;
    int cio = r >> 6;
    int kz = kpos >> 4, ky = (kpos >> 2) & 3, kx = kpos & 3;
    w2s[cio * 784 + kz * 196 + ky * 40 + (kx << 3) + ci] =
        w2[(((ci << 3) + cio) << 6) + kpos];
  }
  for (int l = tid; l < 1024; l += 256) {
    int c4 = l & 3, pair = (l >> 2) & 1, kh = (l >> 3) & 3, kd = (l >> 5) & 3,
        cio = l >> 7;
    int base = (((c4 << 3) + cio) << 6) + (kd << 4) + (kh << 2) + (pair << 1);
    w3p[l] = (unsigned)f2bf(w3[base]) | ((unsigned)f2bf(w3[base + 1]) << 16);
  }

  float acc[4][4];  // [c4][i]
#pragma unroll
  for (int a = 0; a < 4; ++a)
#pragma unroll
    for (int i = 0; i < 4; ++i) acc[a][i] = 0.f;

  const int xh = tid & 1, yq = (tid >> 1) & 15, zq = tid >> 5;

  for (int cio = 0; cio < 8; ++cio) {
    __syncthreads();  // prev conv done reading win (covers staging too)
    const float b2c = b2[cio];
    // ---- fill window: 1224 units = (wz 18) x (wy 34) x (half 2)
    for (int u = tid; u < 1224; u += 256) {
      int wz = u / 68;
      int rem = u - wz * 68;
      int wy = rem >> 1;
      int half = rem & 1;
      unsigned* wrow = win_d + (wz * 34 + wy) * 12;
      int qz = Qz0 + wz, qy = Qy0 + wy;
      if ((unsigned)qz < 64u && (unsigned)qy < 64u) {
        int kz = qz & 3, ky = qy & 3;
        int uzp = (qz >> 2) - Uz0, uyp = (qy >> 2) - Uy0;
        const float* w2b = w2s + cio * 784 + kz * 196 + ky * 40;
        f32x4 w2v[4][2];
#pragma unroll
        for (int kx = 0; kx < 4; ++kx) {
          w2v[kx][0] = *(const f32x4*)(w2b + (kx << 3));
          w2v[kx][1] = *(const f32x4*)(w2b + (kx << 3) + 4);
        }
        const float* h1b = h1s + uzp * 520 + uyp * 52;
#define DOT8(cell, kx)                                                       \
  ({                                                                         \
    const float* hp_ = h1b + ((cell) << 3);                                  \
    f32x4 h0_ = *(const f32x4*)hp_;                                          \
    f32x4 h4_ = *(const f32x4*)(hp_ + 4);                                    \
    f32x4 wa_ = w2v[kx][0], wb_ = w2v[kx][1];                                \
    h0_.x * wa_.x + h0_.y * wa_.y + h0_.z * wa_.z + h0_.w * wa_.w +          \
        h4_.x * wb_.x + h4_.y * wb_.y + h4_.z * wb_.z + h4_.w * wb_.w;       \
  })
        if (half == 0) {  // wx 0..7: cell0(kx3,guard), cell1 kx0-3, cell2 kx0-2
          float vals[8];
          vals[0] = (Qx0 >= 0) ? fast_tanh(DOT8(0, 3) + b2c) : 0.f;
#pragma unroll
          for (int kx = 0; kx < 4; ++kx)
            vals[1 + kx] = fast_tanh(DOT8(1, kx) + b2c);
#pragma unroll
          for (int kx = 0; kx < 3; ++kx)
            vals[5 + kx] = fast_tanh(DOT8(2, kx) + b2c);
          uint4 s0;
          s0.x = f2bf(vals[0]) | ((unsigned)f2bf(vals[1]) << 16);
          s0.y = f2bf(vals[2]) | ((unsigned)f2bf(vals[3]) << 16);
          s0.z = f2bf(vals[4]) | ((unsigned)f2bf(vals[5]) << 16);
          s0.w = f2bf(vals[6]) | ((unsigned)f2bf(vals[7]) << 16);
          *(uint4*)wrow = s0;
        } else {  // wx 8..17: cell2 kx3, cell3 kx0-3, cell4 kx0-3, cell5 kx0(guard)
          float vals[10];
          vals[0] = fast_tanh(DOT8(2, 3) + b2c);
#pragma unroll
          for (int kx = 0; kx < 4; ++kx)
            vals[1 + kx] = fast_tanh(DOT8(3, kx) + b2c);
#pragma unroll
          for (int kx = 0; kx < 4; ++kx)
            vals[5 + kx] = fast_tanh(DOT8(4, kx) + b2c);
          vals[9] = (Qx0 + 17 < 64) ? fast_tanh(DOT8(5, 0) + b2c) : 0.f;
          uint4 s1;
          s1.x = f2bf(vals[0]) | ((unsigned)f2bf(vals[1]) << 16);
          s1.y = f2bf(vals[2]) | ((unsigned)f2bf(vals[3]) << 16);
          s1.z = f2bf(vals[4]) | ((unsigned)f2bf(vals[5]) << 16);
          s1.w = f2bf(vals[6]) | ((unsigned)f2bf(vals[7]) << 16);
          *(uint4*)(wrow + 4) = s1;
          wrow[8] = f2bf(vals[8]) | ((unsigned)f2bf(vals[9]) << 16);
        }
#undef DOT8
      } else {
        uint4 zz;
        zz.x = zz.y = zz.z = zz.w = 0u;
        if (half == 0) {
          *(uint4*)wrow = zz;
        } else {
          *(uint4*)(wrow + 4) = zz;
          wrow[8] = 0u;
        }
      }
    }
    __syncthreads();
    // ---- conv3 accumulation for this cio (packed bf16 dot2)
#pragma unroll
    for (int kd = 0; kd < 4; ++kd) {
      int wz = (zq << 1) + kd;
#pragma unroll
      for (int kh = 0; kh < 4; ++kh) {
        int wy = (yq << 1) + kh;
        const unsigned* rowp = win_d + (wz * 34 + wy) * 12 + (xh << 2);
        uint4 rv = *(const uint4*)rowp;
        unsigned r4 = rowp[4];
        unsigned r[5] = {rv.x, rv.y, rv.z, rv.w, r4};
        const uint4* wp =
            (const uint4*)w3p + (((cio << 4) + (kd << 2) + kh) << 1);
        uint4 wAv = wp[0], wBv = wp[1];
        unsigned wA[4] = {wAv.x, wAv.y, wAv.z, wAv.w};
        unsigned wB[4] = {wBv.x, wBv.y, wBv.z, wBv.w};
#pragma unroll
        for (int c4 = 0; c4 < 4; ++c4) {
#pragma unroll
          for (int i = 0; i < 4; ++i) {
            float a0 = dot2bf(r[i], wA[c4], acc[c4][i]);
            acc[c4][i] = dot2bf(r[i + 1], wB[c4], a0);
          }
        }
      }
    }
  }
  // ---- epilogue: + b3, store to (B, C, 32,32,32, T) with t innermost
  const int b = bt >> 3, t8 = bt & 7;
  const int z = Z0 + zq;
  const int y = Y0 + yq;
#pragma unroll
  for (int c4 = 0; c4 < 4; ++c4) {
    float bias = b3[c4];
#pragma unroll
    for (int i = 0; i < 4; ++i) {
      int xx = X0 + (xh << 2) + i;
      out[(((((b << 2) + c4) * 32 + z) * 32 + y) * 32 + xx) << 3 | t8] =
          acc[c4][i] + bias;
    }
  }
}

extern "C" void kernel_launch(void* const* d_in, const int* in_sizes, int n_in,
                              void* d_out, int out_size, void* d_ws,
                              size_t ws_size, hipStream_t stream) {
  (void)in_sizes; (void)n_in; (void)out_size;
  const float* x = (const float*)d_in[0];
  const float* w1 = (const float*)d_in[1];
  const float* b1 = (const float*)d_in[2];
  const float* w2 = (const float*)d_in[3];
  const float* b2 = (const float*)d_in[4];
  const float* w3 = (const float*)d_in[5];
  const float* b3 = (const float*)d_in[6];
  float* out = (float*)d_out;
  float* part = (float*)d_ws;

  const size_t plane_bytes = (size_t)16 * 8 * 4096 * 4;  // 2 MB per split
  int nsplit = (ws_size >= 4 * plane_bytes) ? 4
               : (ws_size >= 2 * plane_bytes) ? 2 : 1;
  if (nsplit == 4)
    k_stage1<8><<<dim3(512), dim3(256), 0, stream>>>(x, w1, part);
  else if (nsplit == 2)
    k_stage1<16><<<dim3(256), dim3(256), 0, stream>>>(x, w1, part);
  else
    k_stage1<32><<<dim3(128), dim3(256), 0, stream>>>(x, w1, part);
  k_stage23<<<dim3(512), dim3(256), 0, stream>>>(part, w2, b2, w3, b3, b1, out,
                                                 nsplit);
}

// Round 4
// 163.625 us; speedup vs baseline: 1.1245x; 1.1245x over previous
//
#include <hip/hip_runtime.h>
#include <cstdint>

typedef short bf16x8 __attribute__((ext_vector_type(8)));
typedef float f32x4 __attribute__((ext_vector_type(4)));

__device__ __forceinline__ unsigned short f2bf(float f) {
  unsigned u = __builtin_bit_cast(unsigned, f);
  u += 0x7fffu + ((u >> 16) & 1u);  // RNE
  return (unsigned short)(u >> 16);
}
__device__ __forceinline__ float bflo(unsigned u) {
  return __builtin_bit_cast(float, u << 16);
}
__device__ __forceinline__ float bfhi(unsigned u) {
  return __builtin_bit_cast(float, u & 0xffff0000u);
}
__device__ __forceinline__ float fast_tanh(float x) {
  float e = __builtin_amdgcn_exp2f(x * 2.885390081777927f);
  return 1.0f - 2.0f * __builtin_amdgcn_rcpf(e + 1.0f);
}

#if __has_builtin(__builtin_amdgcn_fdot2_f32_bf16)
typedef __bf16 bf16x2 __attribute__((ext_vector_type(2)));
__device__ __forceinline__ float dot2bf(unsigned a, unsigned b, float c) {
  return __builtin_amdgcn_fdot2_f32_bf16(__builtin_bit_cast(bf16x2, a),
                                         __builtin_bit_cast(bf16x2, b), c,
                                         false);
}
#else
__device__ __forceinline__ float dot2bf(unsigned a, unsigned b, float c) {
  c = fmaf(bflo(a), bflo(b), c);
  c = fmaf(bfhi(a), bfhi(b), c);
  return c;
}
#endif

// ---------------------------------------------------------------------------
// Stage 1: per-(ks,bt,co) partial GEMM, M=64(ipos) N=64(kpos) K=1024/nsplit.
// Register ping-pong prefetch; epilogue transposes C through LDS to pos-linear
// then scatters dwords into CHANNEL-LAST part[ks][bt][pos][ci] (L2-absorbed).
// No bias/tanh here (deferred; partials are linear).
// ---------------------------------------------------------------------------
template <int ITERS>
__global__ __launch_bounds__(256) void k_stage1(const float* __restrict__ x,
                                                const float* __restrict__ w1,
                                                float* __restrict__ part) {
  __shared__ __align__(16) char lds_raw[64 * 65 * 4];      // 16640 B
  unsigned short* As = (unsigned short*)lds_raw;           // 64 rows * 40 hw
  unsigned short* Bs = (unsigned short*)(lds_raw + 5120);  // 64 rows * 40 hw
  float* Cs = (float*)lds_raw;                             // 64 x 65 fp32

  const int tid = threadIdx.x;
  const int ks = blockIdx.x >> 7;
  const int bt = (blockIdx.x >> 3) & 15;
  const int co = blockIdx.x & 7;
  const int w = tid >> 6, lane = tid & 63, lm = lane & 15, q = lane >> 4;
  const int rrow = tid & 63, kgr = tid >> 6;

  f32x4 acc[4];
#pragma unroll
  for (int i = 0; i < 4; ++i) acc[i] = (f32x4){0.f, 0.f, 0.f, 0.f};

  const float* gA = x + (bt << 16) + ((size_t)(ks * ITERS * 32) << 6);
  const float* gB = w1 + (co << 6) + (size_t)(ks * ITERS * 32) * 512;

  float va[2][8], vb[2][8];
#define S1_LOAD(buf, it)                            \
  {                                                 \
    const int kb = (it) * 32 + (kgr << 3);          \
    _Pragma("unroll") for (int j = 0; j < 8; ++j) { \
      va[buf][j] = gA[((kb + j) << 6) | rrow];      \
      vb[buf][j] = gB[(kb + j) * 512 + rrow];       \
    }                                               \
  }
  S1_LOAD(0, 0);
#pragma unroll
  for (int it = 0; it < ITERS; ++it) {
    const int cur = it & 1;
    if (it + 1 < ITERS) S1_LOAD(cur ^ 1, it + 1);
    uint4 pa, pb;
    pa.x = f2bf(va[cur][0]) | ((unsigned)f2bf(va[cur][1]) << 16);
    pa.y = f2bf(va[cur][2]) | ((unsigned)f2bf(va[cur][3]) << 16);
    pa.z = f2bf(va[cur][4]) | ((unsigned)f2bf(va[cur][5]) << 16);
    pa.w = f2bf(va[cur][6]) | ((unsigned)f2bf(va[cur][7]) << 16);
    pb.x = f2bf(vb[cur][0]) | ((unsigned)f2bf(vb[cur][1]) << 16);
    pb.y = f2bf(vb[cur][2]) | ((unsigned)f2bf(vb[cur][3]) << 16);
    pb.z = f2bf(vb[cur][4]) | ((unsigned)f2bf(vb[cur][5]) << 16);
    pb.w = f2bf(vb[cur][6]) | ((unsigned)f2bf(vb[cur][7]) << 16);
    *(uint4*)&As[rrow * 40 + (kgr << 3)] = pa;
    *(uint4*)&Bs[rrow * 40 + (kgr << 3)] = pb;
    __syncthreads();
    bf16x8 a = *(const bf16x8*)&As[((w << 4) + lm) * 40 + (q << 3)];
#pragma unroll
    for (int nf = 0; nf < 4; ++nf) {
      bf16x8 b = *(const bf16x8*)&Bs[((nf << 4) + lm) * 40 + (q << 3)];
      acc[nf] = __builtin_amdgcn_mfma_f32_16x16x32_bf16(a, b, acc[nf], 0, 0, 0);
    }
    __syncthreads();
  }
#undef S1_LOAD
  // ---- epilogue: C -> LDS transpose -> pos-linear scatter (stride 8 dw)
#pragma unroll
  for (int nf = 0; nf < 4; ++nf)
#pragma unroll
    for (int r = 0; r < 4; ++r) {
      int m = (w << 4) + (q << 2) + r;
      int n = (nf << 4) + lm;
      Cs[m * 65 + n] = acc[nf][r];
    }
  __syncthreads();
  float* dst = part + (((size_t)((ks << 4) + bt)) << 15) + co;
#pragma unroll
  for (int j = 0; j < 16; ++j) {
    int pos = (tid << 4) + j;
    int z = pos >> 8, y = (pos >> 4) & 15, xx = pos & 15;
    int m = ((z >> 2) << 4) + ((y >> 2) << 2) + (xx >> 2);
    int n = ((z & 3) << 4) + ((y & 3) << 2) + (xx & 3);
    dst[pos << 3] = Cs[m * 65 + n];
  }
}

// ---------------------------------------------------------------------------
// Fused stage 2+3, 512 threads/block. Staging sums K-split partials
// (channel-last, coalesced) + b1 + tanh into PACKED BF16 h1s; w2 packed bf16
// ci-pairs. Fill uses dot2 chains. Conv: thread = (xh,yq,zq,ch) -> 2co x 4x.
// ---------------------------------------------------------------------------
__global__ __launch_bounds__(512) void k_stage23(
    const float* __restrict__ part, const float* __restrict__ w2,
    const float* __restrict__ b2, const float* __restrict__ w3,
    const float* __restrict__ b3, const float* __restrict__ b1,
    float* __restrict__ out, int nsplit) {
  __shared__ __align__(16) unsigned win_d[18 * 34 * 12];  // 29376 B
  __shared__ __align__(16) unsigned h1p[6 * 240];         // bf16 pairs, 5760 B
  __shared__ __align__(16) unsigned w2p[8 * 320];         // bf16 pairs, 10240 B
  __shared__ __align__(16) unsigned w3p[1024];            // [cio][kd][kh][pair][c4]

  const int tid = threadIdx.x;
  const int bid = blockIdx.x;
  const int bt = bid >> 5;
  const int tile = bid & 31;
  const int tz = tile >> 3, ty = (tile >> 2) & 1, tx = tile & 3;
  const int Z0 = tz << 3, Y0 = ty << 4, X0 = tx << 3;
  const int Qz0 = (Z0 << 1) - 1, Qy0 = (Y0 << 1) - 1, Qx0 = (X0 << 1) - 1;
  const int Uz0 = (tz << 2) - 1, Uy0 = (ty << 3) - 1, Ux0 = (tx << 2) - 1;

  // ---- staging: h1 = tanh(sum_s part + b1), coalesced reads, bf16 LDS
  for (int l = tid; l < 2880; l += 512) {
    int ci = l & 7;
    int sp = l >> 3;
    int ux = sp % 6;
    int t1 = sp / 6;
    int uy = t1 % 10;
    int uz = t1 / 10;
    int gz = Uz0 + uz, gy = Uy0 + uy, gx = Ux0 + ux;
    float v = 0.f;
    if ((unsigned)gz < 16u && (unsigned)gy < 16u && (unsigned)gx < 16u) {
      const float* p =
          part + (((size_t)bt << 12) + (gz << 8) + (gy << 4) + gx) * 8 + ci;
      float s = b1[ci];
      for (int sg = 0; sg < nsplit; ++sg) s += p[(size_t)sg << 19];
      v = fast_tanh(s);
    }
    ((unsigned short*)h1p)[uz * 480 + uy * 48 + (ux << 3) + ci] = f2bf(v);
  }
  // w2 packed: dword = [cio][kz*4+ky (stride 20dw)][kx*4 + jpair]
  for (int l = tid; l < 2048; l += 512) {
    int j = l & 3, kx = (l >> 2) & 3, kzy = (l >> 4) & 15, cio = l >> 8;
    int kpos = (kzy << 2) + kx;
    float w0 = w2[(((j << 1) << 3) + cio) * 64 + kpos];
    float w1v = w2[((((j << 1) + 1) << 3) + cio) * 64 + kpos];
    w2p[cio * 320 + kzy * 20 + (kx << 2) + j] =
        (unsigned)f2bf(w0) | ((unsigned)f2bf(w1v) << 16);
  }
  for (int l = tid; l < 1024; l += 512) {
    int c4 = l & 3, pair = (l >> 2) & 1, kh = (l >> 3) & 3, kd = (l >> 5) & 3,
        cio = l >> 7;
    int base = (((c4 << 3) + cio) << 6) + (kd << 4) + (kh << 2) + (pair << 1);
    w3p[l] = (unsigned)f2bf(w3[base]) | ((unsigned)f2bf(w3[base + 1]) << 16);
  }

  float acc[2][4];  // [cc][i]
#pragma unroll
  for (int a = 0; a < 2; ++a)
#pragma unroll
    for (int i = 0; i < 4; ++i) acc[a][i] = 0.f;

  const int xh = tid & 1, yq = (tid >> 1) & 15, zq = (tid >> 5) & 7,
            ch = tid >> 8;

  for (int cio = 0; cio < 8; ++cio) {
    __syncthreads();  // prev conv done reading win (covers staging too)
    const float b2c = b2[cio];
    // ---- fill window: 1224 units = (wz 18) x (wy 34) x (half 2)
    for (int u = tid; u < 1224; u += 512) {
      int wz = u / 68;
      int rem = u - wz * 68;
      int wy = rem >> 1;
      int half = rem & 1;
      unsigned* wrow = win_d + (wz * 34 + wy) * 12;
      int qz = Qz0 + wz, qy = Qy0 + wy;
      if ((unsigned)qz < 64u && (unsigned)qy < 64u) {
        int kz = qz & 3, ky = qy & 3;
        int uzp = (qz >> 2) - Uz0, uyp = (qy >> 2) - Uy0;
        const unsigned* w2b = w2p + cio * 320 + ((kz << 2) + ky) * 20;
        uint4 wv[4];
#pragma unroll
        for (int kx = 0; kx < 4; ++kx) wv[kx] = *(const uint4*)(w2b + (kx << 2));
        const unsigned* h1b = h1p + uzp * 240 + uyp * 24;
#define DOT8(hc, kx)                                               \
  dot2bf((hc).w, wv[kx].w,                                         \
         dot2bf((hc).z, wv[kx].z,                                  \
                dot2bf((hc).y, wv[kx].y, dot2bf((hc).x, wv[kx].x, b2c))))
        if (half == 0) {  // wx 0..7: cell0 kx3(guard), cell1 kx0-3, cell2 kx0-2
          uint4 h0 = *(const uint4*)(h1b);
          uint4 h1c = *(const uint4*)(h1b + 4);
          uint4 h2c = *(const uint4*)(h1b + 8);
          float vals[8];
          vals[0] = (Qx0 >= 0) ? fast_tanh(DOT8(h0, 3)) : 0.f;
#pragma unroll
          for (int kx = 0; kx < 4; ++kx) vals[1 + kx] = fast_tanh(DOT8(h1c, kx));
#pragma unroll
          for (int kx = 0; kx < 3; ++kx) vals[5 + kx] = fast_tanh(DOT8(h2c, kx));
          uint4 s0;
          s0.x = f2bf(vals[0]) | ((unsigned)f2bf(vals[1]) << 16);
          s0.y = f2bf(vals[2]) | ((unsigned)f2bf(vals[3]) << 16);
          s0.z = f2bf(vals[4]) | ((unsigned)f2bf(vals[5]) << 16);
          s0.w = f2bf(vals[6]) | ((unsigned)f2bf(vals[7]) << 16);
          *(uint4*)wrow = s0;
        } else {  // wx 8..17: cell2 kx3, cell3 kx0-3, cell4 kx0-3, cell5 kx0(guard)
          uint4 h2c = *(const uint4*)(h1b + 8);
          uint4 h3 = *(const uint4*)(h1b + 12);
          uint4 h4 = *(const uint4*)(h1b + 16);
          uint4 h5 = *(const uint4*)(h1b + 20);
          float vals[10];
          vals[0] = fast_tanh(DOT8(h2c, 3));
#pragma unroll
          for (int kx = 0; kx < 4; ++kx) vals[1 + kx] = fast_tanh(DOT8(h3, kx));
#pragma unroll
          for (int kx = 0; kx < 4; ++kx) vals[5 + kx] = fast_tanh(DOT8(h4, kx));
          vals[9] = (Qx0 + 17 < 64) ? fast_tanh(DOT8(h5, 0)) : 0.f;
          uint4 s1;
          s1.x = f2bf(vals[0]) | ((unsigned)f2bf(vals[1]) << 16);
          s1.y = f2bf(vals[2]) | ((unsigned)f2bf(vals[3]) << 16);
          s1.z = f2bf(vals[4]) | ((unsigned)f2bf(vals[5]) << 16);
          s1.w = f2bf(vals[6]) | ((unsigned)f2bf(vals[7]) << 16);
          *(uint4*)(wrow + 4) = s1;
          wrow[8] = f2bf(vals[8]) | ((unsigned)f2bf(vals[9]) << 16);
        }
#undef DOT8
      } else {
        uint4 zz;
        zz.x = zz.y = zz.z = zz.w = 0u;
        if (half == 0) {
          *(uint4*)wrow = zz;
        } else {
          *(uint4*)(wrow + 4) = zz;
          wrow[8] = 0u;
        }
      }
    }
    __syncthreads();
    // ---- conv3 accumulation for this cio (packed bf16 dot2), 2 co/thread
#pragma unroll
    for (int kd = 0; kd < 4; ++kd) {
      int wz = (zq << 1) + kd;
#pragma unroll
      for (int kh = 0; kh < 4; ++kh) {
        int wy = (yq << 1) + kh;
        const unsigned* rowp = win_d + (wz * 34 + wy) * 12 + (xh << 2);
        uint4 rv = *(const uint4*)rowp;
        unsigned r4 = rowp[4];
        unsigned r[5] = {rv.x, rv.y, rv.z, rv.w, r4};
        const unsigned* wp = w3p + (((cio << 4) + (kd << 2) + kh) << 3);
        unsigned wA[2] = {wp[(ch << 1)], wp[(ch << 1) + 1]};
        unsigned wB[2] = {wp[4 + (ch << 1)], wp[5 + (ch << 1)]};
#pragma unroll
        for (int cc = 0; cc < 2; ++cc) {
#pragma unroll
          for (int i = 0; i < 4; ++i) {
            float a0 = dot2bf(r[i], wA[cc], acc[cc][i]);
            acc[cc][i] = dot2bf(r[i + 1], wB[cc], a0);
          }
        }
      }
    }
  }
  // ---- epilogue: + b3, store to (B, C, 32,32,32, T) with t innermost
  const int b = bt >> 3, t8 = bt & 7;
  const int z = Z0 + zq;
  const int y = Y0 + yq;
#pragma unroll
  for (int cc = 0; cc < 2; ++cc) {
    int c4 = (ch << 1) + cc;
    float bias = b3[c4];
#pragma unroll
    for (int i = 0; i < 4; ++i) {
      int xx = X0 + (xh << 2) + i;
      out[(((((b << 2) + c4) * 32 + z) * 32 + y) * 32 + xx) << 3 | t8] =
          acc[cc][i] + bias;
    }
  }
}

extern "C" void kernel_launch(void* const* d_in, const int* in_sizes, int n_in,
                              void* d_out, int out_size, void* d_ws,
                              size_t ws_size, hipStream_t stream) {
  (void)in_sizes; (void)n_in; (void)out_size;
  const float* x = (const float*)d_in[0];
  const float* w1 = (const float*)d_in[1];
  const float* b1 = (const float*)d_in[2];
  const float* w2 = (const float*)d_in[3];
  const float* b2 = (const float*)d_in[4];
  const float* w3 = (const float*)d_in[5];
  const float* b3 = (const float*)d_in[6];
  float* out = (float*)d_out;
  float* part = (float*)d_ws;

  const size_t plane_bytes = (size_t)16 * 8 * 4096 * 4;  // 2 MB per split
  int nsplit = (ws_size >= 4 * plane_bytes) ? 4
               : (ws_size >= 2 * plane_bytes) ? 2 : 1;
  if (nsplit == 4)
    k_stage1<8><<<dim3(512), dim3(256), 0, stream>>>(x, w1, part);
  else if (nsplit == 2)
    k_stage1<16><<<dim3(256), dim3(256), 0, stream>>>(x, w1, part);
  else
    k_stage1<32><<<dim3(128), dim3(256), 0, stream>>>(x, w1, part);
  k_stage23<<<dim3(512), dim3(512), 0, stream>>>(part, w2, b2, w3, b3, b1, out,
                                                 nsplit);
}